// Round 20
// baseline (374.432 us; speedup 1.0000x reference)
//
#include <hip/hip_runtime.h>
#include <math.h>

typedef __attribute__((ext_vector_type(8))) short bf16x8;
typedef __attribute__((ext_vector_type(4))) float f32x4;
typedef __attribute__((ext_vector_type(4))) unsigned u32x4;

// ---------------- workspace layout (u32 offsets) ----------------
#define H1P_OFF  0ull
#define H2P_OFF  35143680ull
#define WQ2H_OFF 53526528ull
#define WQ3H_OFF 54050816ull
#define EQ_OFF   54247424ull
#define EN_OFF   54280192ull
#define HIST_OFF 54280704ull   // 8 replicas x 512
#define SSEP_OFF 54284800ull   // 1024 partials
#define WQ1H_OFF 54285824ull

__device__ inline unsigned short f2bf(float f) {
  unsigned u = __builtin_bit_cast(unsigned, f);
  return (unsigned short)((u + 0x7fffu + ((u >> 16) & 1u)) >> 16);  // RNE
}
__device__ inline float bf2f(unsigned short h) {
  return __builtin_bit_cast(float, (unsigned)h << 16);
}
__device__ inline unsigned packsplit(float v) {
  unsigned short h = f2bf(v);
  unsigned short l = f2bf(v - bf2f(h));
  return (unsigned)h | ((unsigned)l << 16);
}
#define SEL_HI 0x05040100u
#define SEL_LO 0x07060302u
__device__ inline bf16x8 mkfrag(const u32x4 p, const u32x4 q, unsigned sel) {
  u32x4 r;
  r[0] = __builtin_amdgcn_perm(p[1], p[0], sel);
  r[1] = __builtin_amdgcn_perm(p[3], p[2], sel);
  r[2] = __builtin_amdgcn_perm(q[1], q[0], sel);
  r[3] = __builtin_amdgcn_perm(q[3], q[2], sel);
  return __builtin_bit_cast(bf16x8, r);
}

// ======= merged prep: weight/emb repack + halo zeroing (one launch) ==========
// blocks [0,2048): wq2 | [2048,2816): wq3 | [2816,2848): wq1 |
// [2848,2976): eq+enorm | [2976,12384): halo zeroing
__global__ void pack_all_k(const float* __restrict__ w1, const float* __restrict__ w2,
                           const float* __restrict__ w3, const float* __restrict__ emb,
                           unsigned short* __restrict__ wh1, unsigned short* __restrict__ wh2,
                           unsigned short* __restrict__ wh3, unsigned* __restrict__ eq,
                           float* __restrict__ enorm,
                           unsigned* __restrict__ h1p, unsigned* __restrict__ h2p) {
  int blk = blockIdx.x;
  if (blk < 2048) {                      // wq2: 524288 u16
    int i = blk * 256 + threadIdx.x;
    int j = i & 7, l = (i >> 3) & 63, fg = (i >> 9) & 15, ks = i >> 13;
    int row = fg * 16 + (l & 15);
    int k = ks * 32 + (l >> 4) * 8 + j;
    wh2[i] = f2bf(w2[row * 2048 + k]);
  } else if (blk < 2816) {               // wq3: 196608 u16
    int i = (blk - 2048) * 256 + threadIdx.x;
    int j = i & 7, l = (i >> 3) & 63, fg = (i >> 9) & 3, ks = i >> 11;
    int row = fg * 16 + (l & 15);
    int k = ks * 32 + (l >> 4) * 8 + j;
    int ci = k / 12, rb = k - ci * 12, kh = rb >> 2, kw = rb & 3;
    wh3[i] = (kw < 3) ? f2bf(w3[((row * 256 + ci) * 3 + kh) * 3 + kw]) : (unsigned short)0;
  } else if (blk < 2848) {               // wq1: 8192 u16
    int i = (blk - 2816) * 256 + threadIdx.x;
    int j = i & 7, l = (i >> 3) & 63, fg = (i >> 9) & 7, ks = i >> 12;
    int row = fg * 16 + (l & 15);
    int k = ks * 32 + (l >> 4) * 8 + j;
    int ci = k >> 4, r = k & 15, kh = r >> 2, kw = r & 3;
    wh1[i] = (ci < 3) ? f2bf(w1[((row * 3 + ci) * 4 + kh) * 4 + kw]) : (unsigned short)0;
  } else if (blk < 2976) {               // eq: 32768 u32 + enorm 512
    int i = (blk - 2848) * 256 + threadIdx.x;
    if (i < 32768) {
      int e = i & 3, l = (i >> 2) & 63, j = (i >> 8) & 1, fg = (i >> 9) & 31, ks = i >> 14;
      int row = fg * 16 + (l & 15);
      int d = ks * 32 + (l >> 4) * 8 + j * 4 + e;
      eq[i] = packsplit(emb[row * 64 + d]);
    }
    if (i < 512) {
      float s = 0.f;
#pragma unroll
      for (int d = 0; d < 64; ++d) { float e = emb[i * 64 + d]; s += e * e; }
      enorm[i] = s;
    }
  } else {                               // halo zeroing
    int i = (blk - 2976) * 256 + threadIdx.x;
    if (i < 2048 * 520) {
      int p = i / 520, c = i - p * 520; int r, cc;
      if (c < 132)      { r = 0;   cc = c; }
      else if (c < 264) { r = 129; cc = c - 132; }
      else if (c < 392) { r = c - 264 + 1; cc = 0; }
      else              { r = c - 392 + 1; cc = 129; }
      h1p[(size_t)p * 130 * 132 + r * 132 + cc] = 0u;
    } else {
      int j = i - 2048 * 520;
      if (j >= 4096 * 328) return;
      int p = j / 328, c = j - p * 328; int r, cc;
      if (c < 68)       { r = 0;  cc = c; }
      else if (c < 136) { r = 65; cc = c - 68; }
      else { int c2 = c - 136; int which = c2 >> 6; r = 1 + (c2 & 63);
             cc = (which == 0) ? 0 : (which == 1 ? 65 : 66); }
      h2p[(size_t)p * 66 * 68 + r * 68 + cc] = 0u;
    }
  }
}

// ====== pipelined implicit-GEMM conv, 2-term split-bf16 MFMA ==================
// R20: conv2 moves to wave tile 64m x 128n (NWX=2, NWC=2, MR=128, D=1) —
// doubles MFMAs per A-byte (LDS per-work ~halves). B single-buffered with
// per-nf DEFERRED prefetch (BDEF; R9-proven pattern) to fit registers:
// ~105 VGPR + 128 AGPR acc <= 256. All else = R18/R19.
template <int IC, int KHW, int OC, int IHP, int IWP, int S, int NWX, int NWC,
          int YB, bool WIDE, int OSR, int OSP, int OPAD, bool SPLIT_OUT, int D,
          bool XSRC, bool BDEF>
__global__ __launch_bounds__(256, 2) void convmm_k(const unsigned* __restrict__ inp,
                                                   const float* __restrict__ xsrc,
                                                   const unsigned short* __restrict__ wqh,
                                                   const float* __restrict__ bias,
                                                   unsigned* __restrict__ outp,
                                                   float* __restrict__ outf) {
  constexpr int K = IC * KHW;
  constexpr int KSUPER = K / (32 * D);
  constexpr int FGTOT = OC / 16;
  constexpr int NFRAG = OC / NWC / 16;
  constexpr int MR = 64 * NWX;
  constexpr int CELLS = (MR / 32) * D;
  constexpr int GPLANE = MR * 16;
  constexpr int HBYTES = MR * 64 * D;
  constexpr int ABYTES = MR * 128 * D;
  constexpr int LOG2NWX = (NWX == 2) ? 1 : 0;
  constexpr int LOG2MR = (NWX == 2) ? 7 : 6;

  __shared__ char smem[2 * ABYTES];

  const int tid = threadIdx.x, l = tid & 63, wv = tid >> 6;
  const int orig = (blockIdx.x & 7) * ((int)gridDim.x >> 3) + (blockIdx.x >> 3);
  const int bb = orig >> YB;
  const int y0 = orig & ((1 << YB) - 1);
  const int rsel = l & 15, gp = l >> 4;
  const int mbase = (wv & (NWX - 1)) * 64;
  const int fgbase = (wv >> LOG2NWX) * NFRAG;
  const int nbase = fgbase * 16;

  const int arow = tid & (MR - 1);
  int qs[CELLS];
  const unsigned* abase[CELLS];
#pragma unroll
  for (int c = 0; c < CELLS; ++c) {
    qs[c] = (tid >> LOG2MR) * CELLS + c;
    if constexpr (KHW == 16 && !XSRC) {
      int ci0 = qs[c] >> 2, kh = qs[c] & 3;
      int yl = (WIDE || NWX == 1) ? 0 : (arow >> 6);
      int xc = (WIDE || NWX == 1) ? arow : (arow & 63);
      int ybase = WIDE ? y0 : (y0 * NWX + yl);
      abase[c] = inp + (((size_t)bb * IC + ci0) * IHP + (S * ybase + kh)) * IWP + S * xc;
    }
  }

  f32x4 acc[NFRAG][4];
#pragma unroll
  for (int nf = 0; nf < NFRAG; ++nf)
#pragma unroll
    for (int xf = 0; xf < 4; ++xf) acc[nf][xf] = (f32x4){0.f, 0.f, 0.f, 0.f};

  unsigned avA[CELLS][4], avB[CELLS][4];
  bf16x8 brA[D][NFRAG], brB[D][NFRAG];

  auto ldB1 = [&](int ks, int nf) -> bf16x8 {
    size_t idx = (((size_t)(ks * FGTOT + fgbase + nf) * 64) + l) * 8;
    return *(const bf16x8*)(wqh + idx);
  };
  auto loadA = [&](int ks, unsigned (&av)[CELLS][4]) {
#pragma unroll
    for (int c = 0; c < CELLS; ++c) {
      if constexpr (XSRC) {
        int ci = (qs[c] >> 2) + 2 * D * ks;
        int kh = qs[c] & 3;
        int iy = S * y0 + kh - 1;
        bool yok = (ci < 3) && ((unsigned)iy < 256u);
        const float* xp = xsrc + ((size_t)(bb * 3 + ci) * 256 + iy) * 256;
#pragma unroll
        for (int e = 0; e < 4; ++e) {
          int ix = S * arow + e - 1;
          av[c][e] = (yok && (unsigned)ix < 256u) ? packsplit(xp[ix]) : 0u;
        }
      } else if constexpr (KHW == 16) {
        const unsigned* p = abase[c];
        av[c][0] = p[0]; av[c][1] = p[1]; av[c][2] = p[2]; av[c][3] = p[3];
        abase[c] += (size_t)(2 * D) * IHP * IWP;
      } else {                                   // KHW == 12 (conv3)
        int k = ks * (32 * D) + qs[c] * 4;
        int ci = (k * 5462) >> 16;
        int rb = k - ci * 12;
        int kh = rb >> 2;
        int yl = arow >> 6, x = arow & 63;
        const unsigned* p = inp + (((size_t)bb * IC + ci) * IHP + (y0 * 2 + yl + kh)) * IWP + x;
        av[c][0] = p[0]; av[c][1] = p[1]; av[c][2] = p[2]; av[c][3] = p[3];
      }
    }
  };
  auto writeA = [&](int buf, unsigned (&av)[CELLS][4]) {
    char* base = smem + buf * ABYTES;
#pragma unroll
    for (int cp = 0; cp < CELLS / 2; ++cp) {
      int q0 = qs[2 * cp];
      int off = (q0 >> 1) * GPLANE + (arow << 4);
      u32x4 h, lo;
      h[0]  = __builtin_amdgcn_perm(av[2 * cp][1],     av[2 * cp][0],     SEL_HI);
      h[1]  = __builtin_amdgcn_perm(av[2 * cp][3],     av[2 * cp][2],     SEL_HI);
      h[2]  = __builtin_amdgcn_perm(av[2 * cp + 1][1], av[2 * cp + 1][0], SEL_HI);
      h[3]  = __builtin_amdgcn_perm(av[2 * cp + 1][3], av[2 * cp + 1][2], SEL_HI);
      lo[0] = __builtin_amdgcn_perm(av[2 * cp][1],     av[2 * cp][0],     SEL_LO);
      lo[1] = __builtin_amdgcn_perm(av[2 * cp][3],     av[2 * cp][2],     SEL_LO);
      lo[2] = __builtin_amdgcn_perm(av[2 * cp + 1][1], av[2 * cp + 1][0], SEL_LO);
      lo[3] = __builtin_amdgcn_perm(av[2 * cp + 1][3], av[2 * cp + 1][2], SEL_LO);
      *(u32x4*)(base + off) = h;
      *(u32x4*)(base + HBYTES + off) = lo;
    }
  };
  auto loadB = [&](int ks, bf16x8 (&bh)[D][NFRAG]) {
#pragma unroll
    for (int s = 0; s < D; ++s)
#pragma unroll
      for (int nf = 0; nf < NFRAG; ++nf)
        bh[s][nf] = ldB1(ks * D + s, nf);
  };
  auto step = [&](int ks, bf16x8 (&ch)[D][NFRAG], bf16x8 (&nh)[D][NFRAG],
                  unsigned (&avW)[CELLS][4], unsigned (&avL)[CELLS][4]) {
    const bool hasW = (ks + 1 < KSUPER);
    const bool hasL = (ks + 2 < KSUPER);
    if constexpr (!BDEF) { if (hasW) loadB(ks + 1, nh); }
    if (hasL) loadA(ks + 2, avL);
    const char* bA = smem + (ks & 1) * ABYTES;
#pragma unroll
    for (int s = 0; s < D; ++s) {
      bf16x8 ah[4], al[4];
#pragma unroll
      for (int xf = 0; xf < 4; ++xf) {
        int row = mbase + xf * 16 + rsel;
        ah[xf] = *(const bf16x8*)(bA + (s * 4 + gp) * GPLANE + (row << 4));
        al[xf] = *(const bf16x8*)(bA + HBYTES + (s * 4 + gp) * GPLANE + (row << 4));
      }
#pragma unroll
      for (int nf = 0; nf < NFRAG; ++nf) {
        bf16x8 w;
        if constexpr (BDEF) {
          w = ch[s][nf];
          if (hasW) ch[s][nf] = ldB1(ks + 1, nf);   // deferred prefetch, used next step
        } else {
          w = ch[s][nf];
        }
#pragma unroll
        for (int xf = 0; xf < 4; ++xf) {
          acc[nf][xf] = __builtin_amdgcn_mfma_f32_16x16x32_bf16(w, ah[xf], acc[nf][xf], 0, 0, 0);
          acc[nf][xf] = __builtin_amdgcn_mfma_f32_16x16x32_bf16(w, al[xf], acc[nf][xf], 0, 0, 0);
        }
      }
    }
    if (hasW) writeA((ks & 1) ^ 1, avW);
    __syncthreads();
  };

  loadB(0, brA);
  loadA(0, avA);
  writeA(0, avA);
  if (KSUPER > 1) loadA(1, avB);
  __syncthreads();

#pragma unroll 1
  for (int ks = 0; ks < KSUPER; ks += 2) {   // KSUPER even (2 / 64 / 48)
    step(ks,     brA, brB, avB, avA);
    step(ks + 1, BDEF ? brA : brB, brA, avA, avB);
  }

#pragma unroll
  for (int nf = 0; nf < NFRAG; ++nf) {
    int n0 = nbase + nf * 16 + (l >> 4) * 4;
#pragma unroll
    for (int xf = 0; xf < 4; ++xf) {
      int m = mbase + xf * 16 + rsel;
      int xo, yout;
      if constexpr (WIDE) { xo = m; yout = y0; }
      else { xo = m & 63; yout = y0 * NWX + (m >> 6); }
#pragma unroll
      for (int r = 0; r < 4; ++r) {
        float v = acc[nf][xf][r] + bias[n0 + r];
        if constexpr (SPLIT_OUT) {
          if (v < 0.f) v = 0.f;
          outp[((size_t)bb * OC + n0 + r) * OSP + (size_t)(yout + OPAD) * OSR + (xo + OPAD)] =
              packsplit(v);
        } else {
          outf[((size_t)bb * OC + n0 + r) * OSP + (size_t)yout * OSR + xo] = v;
        }
      }
    }
  }
}

// ============ VQ via MFMA (R8, verified; full 3-term split) ========
__global__ __launch_bounds__(256, 2) void vqmm_k(float* __restrict__ zq,
                                                 const float* __restrict__ emb,
                                                 const unsigned* __restrict__ eq,
                                                 const float* __restrict__ enorm,
                                                 unsigned* __restrict__ hist,
                                                 float* __restrict__ ssep) {
  const int tid = threadIdx.x, l = tid & 63, wv = tid >> 6;
  float* zsrc = zq + (size_t)blockIdx.x * 4096;

  __shared__ float zf[64][64];
  __shared__ unsigned zp[4096];
  __shared__ float candd[4][64];
  __shared__ int   candi[4][64];
  __shared__ int   idxf[64];
  __shared__ unsigned hcnt[512];
  __shared__ float wsse[4];

  for (int i = tid; i < 512; i += 256) hcnt[i] = 0;

#pragma unroll
  for (int p = 0; p < 4; ++p) {
    int idx = p * 256 + tid;
    float4 v = *(const float4*)(zsrc + (size_t)idx * 4);
    int n = idx >> 4, d0 = (idx & 15) * 4;
    zf[n][d0 + 0] = v.x; zf[n][d0 + 1] = v.y;
    zf[n][d0 + 2] = v.z; zf[n][d0 + 3] = v.w;
  }
  __syncthreads();
#pragma unroll
  for (int p = 0; p < 16; ++p) {
    int idx = p * 256 + tid;
    int n = idx >> 6, d = idx & 63;
    zp[(n << 6) + ((((d >> 2) ^ (n & 15)) << 2) | (d & 3))] = packsplit(zf[n][d]);
  }
  __syncthreads();

  f32x4 acc[8][4];
#pragma unroll
  for (int nf = 0; nf < 8; ++nf)
#pragma unroll
    for (int xf = 0; xf < 4; ++xf) acc[nf][xf] = (f32x4){0.f, 0.f, 0.f, 0.f};

  const int rsel = l & 15;
#pragma unroll
  for (int ks = 0; ks < 2; ++ks) {
    bf16x8 ah[4], al[4];
    const int gk = ks * 8 + (l >> 4) * 2;
#pragma unroll
    for (int xf = 0; xf < 4; ++xf) {
      int n = xf * 16 + rsel;
      u32x4 p0 = *(const u32x4*)((const char*)zp + (n << 8) + ((gk ^ (n & 15)) << 4));
      u32x4 p1 = *(const u32x4*)((const char*)zp + (n << 8) + (((gk + 1) ^ (n & 15)) << 4));
      ah[xf] = mkfrag(p0, p1, SEL_HI);
      al[xf] = mkfrag(p0, p1, SEL_LO);
    }
#pragma unroll
    for (int nf = 0; nf < 8; ++nf) {
      int fg = wv * 8 + nf;
      u32x4 b0 = *(const u32x4*)(eq + (((size_t)((ks * 32 + fg) * 2 + 0)) << 8) + (l << 2));
      u32x4 b1 = *(const u32x4*)(eq + (((size_t)((ks * 32 + fg) * 2 + 1)) << 8) + (l << 2));
      bf16x8 wh = mkfrag(b0, b1, SEL_HI);
      bf16x8 wl = mkfrag(b0, b1, SEL_LO);
#pragma unroll
      for (int xf = 0; xf < 4; ++xf) {
        acc[nf][xf] = __builtin_amdgcn_mfma_f32_16x16x32_bf16(wh, ah[xf], acc[nf][xf], 0, 0, 0);
        acc[nf][xf] = __builtin_amdgcn_mfma_f32_16x16x32_bf16(wh, al[xf], acc[nf][xf], 0, 0, 0);
        acc[nf][xf] = __builtin_amdgcn_mfma_f32_16x16x32_bf16(wl, ah[xf], acc[nf][xf], 0, 0, 0);
      }
    }
  }

  float en[8][4];
#pragma unroll
  for (int nf = 0; nf < 8; ++nf)
#pragma unroll
    for (int r = 0; r < 4; ++r)
      en[nf][r] = enorm[wv * 128 + nf * 16 + (l >> 4) * 4 + r];

#pragma unroll
  for (int xf = 0; xf < 4; ++xf) {
    float best = 1e30f; int bidx = 0;
#pragma unroll
    for (int nf = 0; nf < 8; ++nf)
#pragma unroll
      for (int r = 0; r < 4; ++r) {
        int k = wv * 128 + nf * 16 + (l >> 4) * 4 + r;
        float dist = en[nf][r] - 2.f * acc[nf][xf][r];
        if (dist < best || (dist == best && k < bidx)) { best = dist; bidx = k; }
      }
#pragma unroll
    for (int off = 16; off <= 32; off <<= 1) {
      float ob = __shfl_xor(best, off, 64);
      int oi = __shfl_xor(bidx, off, 64);
      if (ob < best || (ob == best && oi < bidx)) { best = ob; bidx = oi; }
    }
    if (l < 16) { candd[wv][xf * 16 + l] = best; candi[wv][xf * 16 + l] = bidx; }
  }
  __syncthreads();
  if (tid < 64) {
    float best = candd[0][tid]; int bidx = candi[0][tid];
#pragma unroll
    for (int w = 1; w < 4; ++w) {
      float ob = candd[w][tid]; int oi = candi[w][tid];
      if (ob < best || (ob == best && oi < bidx)) { best = ob; bidx = oi; }
    }
    idxf[tid] = bidx;
    atomicAdd(&hcnt[bidx], 1u);
  }
  __syncthreads();

  float sse = 0.f;
#pragma unroll
  for (int p = 0; p < 16; ++p) {
    int idx = p * 256 + tid;
    int n = idx >> 6, d = idx & 63;
    float q = emb[idxf[n] * 64 + d];
    float z = zf[n][d];
    float df = q - z;
    sse += df * df;
    zsrc[idx] = q;
  }
#pragma unroll
  for (int off = 32; off > 0; off >>= 1) sse += __shfl_down(sse, off, 64);
  if (l == 0) wsse[wv] = sse;

  unsigned* hr = hist + ((blockIdx.x & 7) << 9);
  __syncthreads();
  for (int i = tid; i < 512; i += 256)
    if (hcnt[i]) atomicAdd(&hr[i], hcnt[i]);
  if (tid == 0) ssep[blockIdx.x] = wsse[0] + wsse[1] + wsse[2] + wsse[3];
}

// ================= finalize =================
__global__ void fin_k(const unsigned* __restrict__ hist,
                      const float* __restrict__ ssep,
                      float* __restrict__ out) {
  __shared__ float red[512];
  __shared__ float sred[512];
  int t = threadIdx.x;
  sred[t] = ssep[t] + ssep[t + 512];
  unsigned c = 0;
#pragma unroll
  for (int r = 0; r < 8; ++r) c += hist[(r << 9) + t];
  float p = (float)c * (1.f / 65536.f);
  red[t] = p * logf(p + 1e-10f);
  __syncthreads();
  for (int s = 256; s > 0; s >>= 1) {
    if (t < s) { red[t] += red[t + s]; sred[t] += sred[t + s]; }
    __syncthreads();
  }
  if (t == 0) {
    out[4194304] = 1.25f * sred[0] * (1.f / 4194304.f);
    out[4194305] = expf(-red[0]);
  }
}

extern "C" void kernel_launch(void* const* d_in, const int* in_sizes, int n_in,
                              void* d_out, int out_size, void* d_ws, size_t ws_size,
                              hipStream_t stream) {
  const float* x   = (const float*)d_in[0];
  const float* w1  = (const float*)d_in[1];
  const float* b1  = (const float*)d_in[2];
  const float* w2  = (const float*)d_in[3];
  const float* b2  = (const float*)d_in[4];
  const float* w3  = (const float*)d_in[5];
  const float* b3  = (const float*)d_in[6];
  const float* emb = (const float*)d_in[7];
  // decoder weights unused: reference output ignores x_recon

  float* out = (float*)d_out;
  unsigned* wsu = (unsigned*)d_ws;
  unsigned* h1p = wsu + H1P_OFF;
  unsigned* h2p = wsu + H2P_OFF;
  unsigned short* wq1h = (unsigned short*)(wsu + WQ1H_OFF);
  unsigned short* wq2h = (unsigned short*)(wsu + WQ2H_OFF);
  unsigned short* wq3h = (unsigned short*)(wsu + WQ3H_OFF);
  unsigned* eqp = wsu + EQ_OFF;
  float* enorm = (float*)(wsu + EN_OFF);
  unsigned* hist = wsu + HIST_OFF;
  float* ssep = (float*)(wsu + SSEP_OFF);

  hipMemsetAsync(wsu + HIST_OFF, 0, 4096 * sizeof(unsigned), stream);

  pack_all_k<<<dim3(12384), dim3(256), 0, stream>>>(w1, w2, w3, emb,
                                                    wq1h, wq2h, wq3h, eqp, enorm,
                                                    h1p, h2p);

  // conv1: 3->128 via direct-x (XSRC), 4x4 s2 p1, WIDE, D=1
  convmm_k<4, 16, 128, 258, 260, 2, 2, 2, 7, true, 132, 17160, 1, true, 1, true, false>
      <<<dim3(2048), dim3(256), 0, stream>>>(nullptr, x, wq1h, b1, h1p, nullptr);
  // conv2: 128->256, 4x4 s2 p1 — NWX=2/NWC=2 (wave 64m x 128n), D=1, B deferred
  convmm_k<128, 16, 256, 130, 132, 2, 2, 2, 5, false, 68, 4488, 1, true, 1, false, true>
      <<<dim3(512), dim3(256), 0, stream>>>(h1p, nullptr, wq2h, b2, h2p, nullptr);
  // conv3: 256->64, 3x3 s1 p1 (NWX=2, NWC=2), D=2
  convmm_k<256, 12, 64, 66, 68, 1, 2, 2, 5, false, 64, 4096, 0, false, 2, false, false>
      <<<dim3(512), dim3(256), 0, stream>>>(h2p, nullptr, wq3h, b3, nullptr, out);

  vqmm_k<<<dim3(1024), dim3(256), 0, stream>>>(out, emb, eqp, enorm, hist, ssep);
  fin_k<<<dim3(1), dim3(512), 0, stream>>>(hist, ssep, out);
}

// Round 21
// 288.350 us; speedup vs baseline: 1.2985x; 1.2985x over previous
//
#include <hip/hip_runtime.h>
#include <math.h>

typedef __attribute__((ext_vector_type(8))) short bf16x8;
typedef __attribute__((ext_vector_type(4))) float f32x4;
typedef __attribute__((ext_vector_type(4))) unsigned u32x4;
typedef __attribute__((ext_vector_type(2))) unsigned u32x2;

// ---------------- workspace layout (u32 offsets) ----------------
#define H1P_OFF  0ull
#define H2P_OFF  35143680ull
#define WQ2H_OFF 53526528ull
#define WQ3H_OFF 54050816ull
#define EQ_OFF   54247424ull
#define EN_OFF   54280192ull
#define HIST_OFF 54280704ull   // 8 replicas x 512
#define SSEP_OFF 54284800ull   // 1024 partials
#define WQ1H_OFF 54285824ull

__device__ inline unsigned short f2bf(float f) {
  unsigned u = __builtin_bit_cast(unsigned, f);
  return (unsigned short)((u + 0x7fffu + ((u >> 16) & 1u)) >> 16);  // RNE
}
__device__ inline float bf2f(unsigned short h) {
  return __builtin_bit_cast(float, (unsigned)h << 16);
}
__device__ inline unsigned packsplit(float v) {
  unsigned short h = f2bf(v);
  unsigned short l = f2bf(v - bf2f(h));
  return (unsigned)h | ((unsigned)l << 16);
}
#define SEL_HI 0x05040100u
#define SEL_LO 0x07060302u
__device__ inline bf16x8 mkfrag(const u32x4 p, const u32x4 q, unsigned sel) {
  u32x4 r;
  r[0] = __builtin_amdgcn_perm(p[1], p[0], sel);
  r[1] = __builtin_amdgcn_perm(p[3], p[2], sel);
  r[2] = __builtin_amdgcn_perm(q[1], q[0], sel);
  r[3] = __builtin_amdgcn_perm(q[3], q[2], sel);
  return __builtin_bit_cast(bf16x8, r);
}

// ======= merged weight/emb repack (one launch) ===============================
// blocks [0,2048): wq2 | [2048,2816): wq3 | [2816,2848): wq1 | [2848,2976): eq+enorm
__global__ void pack_all_k(const float* __restrict__ w1, const float* __restrict__ w2,
                           const float* __restrict__ w3, const float* __restrict__ emb,
                           unsigned short* __restrict__ wh1, unsigned short* __restrict__ wh2,
                           unsigned short* __restrict__ wh3, unsigned* __restrict__ eq,
                           float* __restrict__ enorm) {
  int blk = blockIdx.x;
  if (blk < 2048) {                      // wq2: 524288 u16
    int i = blk * 256 + threadIdx.x;
    int j = i & 7, l = (i >> 3) & 63, fg = (i >> 9) & 15, ks = i >> 13;
    int row = fg * 16 + (l & 15);
    int k = ks * 32 + (l >> 4) * 8 + j;
    wh2[i] = f2bf(w2[row * 2048 + k]);
  } else if (blk < 2816) {               // wq3: 196608 u16
    int i = (blk - 2048) * 256 + threadIdx.x;
    int j = i & 7, l = (i >> 3) & 63, fg = (i >> 9) & 3, ks = i >> 11;
    int row = fg * 16 + (l & 15);
    int k = ks * 32 + (l >> 4) * 8 + j;
    int ci = k / 12, rb = k - ci * 12, kh = rb >> 2, kw = rb & 3;
    wh3[i] = (kw < 3) ? f2bf(w3[((row * 256 + ci) * 3 + kh) * 3 + kw]) : (unsigned short)0;
  } else if (blk < 2848) {               // wq1: 8192 u16
    int i = (blk - 2816) * 256 + threadIdx.x;
    int j = i & 7, l = (i >> 3) & 63, fg = (i >> 9) & 7, ks = i >> 12;
    int row = fg * 16 + (l & 15);
    int k = ks * 32 + (l >> 4) * 8 + j;
    int ci = k >> 4, r = k & 15, kh = r >> 2, kw = r & 3;
    wh1[i] = (ci < 3) ? f2bf(w1[((row * 3 + ci) * 4 + kh) * 4 + kw]) : (unsigned short)0;
  } else {                               // eq: 32768 u32 + enorm 512
    int i = (blk - 2848) * 256 + threadIdx.x;
    if (i < 32768) {
      int e = i & 3, l = (i >> 2) & 63, j = (i >> 8) & 1, fg = (i >> 9) & 31, ks = i >> 14;
      int row = fg * 16 + (l & 15);
      int d = ks * 32 + (l >> 4) * 8 + j * 4 + e;
      eq[i] = packsplit(emb[row * 64 + d]);
    }
    if (i < 512) {
      float s = 0.f;
#pragma unroll
      for (int d = 0; d < 64; ++d) { float e = emb[i * 64 + d]; s += e * e; }
      enorm[i] = s;
    }
  }
}

// ================= halo zeroing (h1p interior written by conv1) ==========
__global__ void halo_k(unsigned* __restrict__ h1p, unsigned* __restrict__ h2p) {
  int i = blockIdx.x * 256 + threadIdx.x;
  if (i < 2048 * 520) {
    int p = i / 520, c = i - p * 520; int r, cc;
    if (c < 132)      { r = 0;   cc = c; }
    else if (c < 264) { r = 129; cc = c - 132; }
    else if (c < 392) { r = c - 264 + 1; cc = 0; }
    else              { r = c - 392 + 1; cc = 129; }
    h1p[(size_t)p * 130 * 132 + r * 132 + cc] = 0u;
  } else {
    int j = i - 2048 * 520;
    if (j >= 4096 * 328) return;
    int p = j / 328, c = j - p * 328; int r, cc;
    if (c < 68)       { r = 0;  cc = c; }
    else if (c < 136) { r = 65; cc = c - 68; }
    else { int c2 = c - 136; int which = c2 >> 6; r = 1 + (c2 & 63);
           cc = (which == 0) ? 0 : (which == 1 ? 65 : 66); }
    h2p[(size_t)p * 66 * 68 + r * 68 + cc] = 0u;
  }
}

// ====== pipelined implicit-GEMM conv, 2-term split-bf16 MFMA ==================
// R21 = R19 exact revert (measured best). R20's NWC=2 wave tile spilled
// (VGPR 128 cap + WRITE_SIZE 70->225MB). Design space mapped: NWC=4,D=2 wins.
template <int IC, int KHW, int OC, int IHP, int IWP, int S, int NWX, int NWC,
          int YB, bool WIDE, int OSR, int OSP, int OPAD, bool SPLIT_OUT, int D, bool XSRC>
__global__ __launch_bounds__(256, 2) void convmm_k(const unsigned* __restrict__ inp,
                                                   const float* __restrict__ xsrc,
                                                   const unsigned short* __restrict__ wqh,
                                                   const float* __restrict__ bias,
                                                   unsigned* __restrict__ outp,
                                                   float* __restrict__ outf) {
  constexpr int K = IC * KHW;
  constexpr int KSUPER = K / (32 * D);
  constexpr int FGTOT = OC / 16;
  constexpr int NFRAG = OC / NWC / 16;
  constexpr int MR = 64 * NWX;
  constexpr int CELLS = (MR / 32) * D;
  constexpr int GPLANE = MR * 16;
  constexpr int HBYTES = MR * 64 * D;
  constexpr int ABYTES = MR * 128 * D;
  constexpr int LOG2NWX = (NWX == 2) ? 1 : 0;
  constexpr int LOG2MR = (NWX == 2) ? 7 : 6;

  __shared__ char smem[2 * ABYTES];

  const int tid = threadIdx.x, l = tid & 63, wv = tid >> 6;
  const int orig = (blockIdx.x & 7) * ((int)gridDim.x >> 3) + (blockIdx.x >> 3);
  const int bb = orig >> YB;
  const int y0 = orig & ((1 << YB) - 1);
  const int rsel = l & 15, gp = l >> 4;
  const int mbase = (wv & (NWX - 1)) * 64;
  const int fgbase = (wv >> LOG2NWX) * NFRAG;
  const int nbase = fgbase * 16;

  const int arow = tid & (MR - 1);
  int qs[CELLS];
  const unsigned* abase[CELLS];
#pragma unroll
  for (int c = 0; c < CELLS; ++c) {
    qs[c] = (tid >> LOG2MR) * CELLS + c;
    if constexpr (KHW == 16 && !XSRC) {
      int ci0 = qs[c] >> 2, kh = qs[c] & 3;
      abase[c] = inp + (((size_t)bb * IC + ci0) * IHP + (S * y0 + kh)) * IWP + S * arow;
    }
  }

  f32x4 acc[NFRAG][4];
#pragma unroll
  for (int nf = 0; nf < NFRAG; ++nf)
#pragma unroll
    for (int xf = 0; xf < 4; ++xf) acc[nf][xf] = (f32x4){0.f, 0.f, 0.f, 0.f};

  unsigned avA[CELLS][4], avB[CELLS][4];
  bf16x8 brA[D][NFRAG], brB[D][NFRAG];

  auto loadA = [&](int ks, unsigned (&av)[CELLS][4]) {
#pragma unroll
    for (int c = 0; c < CELLS; ++c) {
      if constexpr (XSRC) {
        // conv1 direct-x: ci = qs>>2 + 2*D*ks, kh = qs&3; padded coords -1.
        int ci = (qs[c] >> 2) + 2 * D * ks;
        int kh = qs[c] & 3;
        int iy = S * y0 + kh - 1;
        bool yok = (ci < 3) && ((unsigned)iy < 256u);
        const float* xp = xsrc + ((size_t)(bb * 3 + ci) * 256 + iy) * 256;
#pragma unroll
        for (int e = 0; e < 4; ++e) {
          int ix = S * arow + e - 1;
          av[c][e] = (yok && (unsigned)ix < 256u) ? packsplit(xp[ix]) : 0u;
        }
      } else if constexpr (KHW == 16) {
        const unsigned* p = abase[c];
        av[c][0] = p[0]; av[c][1] = p[1]; av[c][2] = p[2]; av[c][3] = p[3];
        abase[c] += (size_t)(2 * D) * IHP * IWP;
      } else {                                   // KHW == 12 (conv3)
        int k = ks * (32 * D) + qs[c] * 4;
        int ci = (k * 5462) >> 16;
        int rb = k - ci * 12;
        int kh = rb >> 2;
        int yl = arow >> 6, x = arow & 63;
        const unsigned* p = inp + (((size_t)bb * IC + ci) * IHP + (y0 * 2 + yl + kh)) * IWP + x;
        av[c][0] = p[0]; av[c][1] = p[1]; av[c][2] = p[2]; av[c][3] = p[3];
      }
    }
  };
  auto writeA = [&](int buf, unsigned (&av)[CELLS][4]) {
    char* base = smem + buf * ABYTES;
#pragma unroll
    for (int cp = 0; cp < CELLS / 2; ++cp) {
      int q0 = qs[2 * cp];
      int off = (q0 >> 1) * GPLANE + (arow << 4);
      u32x4 h, lo;
      h[0]  = __builtin_amdgcn_perm(av[2 * cp][1],     av[2 * cp][0],     SEL_HI);
      h[1]  = __builtin_amdgcn_perm(av[2 * cp][3],     av[2 * cp][2],     SEL_HI);
      h[2]  = __builtin_amdgcn_perm(av[2 * cp + 1][1], av[2 * cp + 1][0], SEL_HI);
      h[3]  = __builtin_amdgcn_perm(av[2 * cp + 1][3], av[2 * cp + 1][2], SEL_HI);
      lo[0] = __builtin_amdgcn_perm(av[2 * cp][1],     av[2 * cp][0],     SEL_LO);
      lo[1] = __builtin_amdgcn_perm(av[2 * cp][3],     av[2 * cp][2],     SEL_LO);
      lo[2] = __builtin_amdgcn_perm(av[2 * cp + 1][1], av[2 * cp + 1][0], SEL_LO);
      lo[3] = __builtin_amdgcn_perm(av[2 * cp + 1][3], av[2 * cp + 1][2], SEL_LO);
      *(u32x4*)(base + off) = h;
      *(u32x4*)(base + HBYTES + off) = lo;
    }
  };
  auto loadB = [&](int ks, bf16x8 (&bh)[D][NFRAG]) {
#pragma unroll
    for (int s = 0; s < D; ++s)
#pragma unroll
      for (int nf = 0; nf < NFRAG; ++nf) {
        size_t idx = (((size_t)((ks * D + s) * FGTOT + fgbase + nf) * 64) + l) * 8;
        bh[s][nf] = *(const bf16x8*)(wqh + idx);
      }
  };
  auto step = [&](int ks, bf16x8 (&ch)[D][NFRAG], bf16x8 (&nh)[D][NFRAG],
                  unsigned (&avW)[CELLS][4], unsigned (&avL)[CELLS][4]) {
    const bool hasW = (ks + 1 < KSUPER);
    const bool hasL = (ks + 2 < KSUPER);
    if (hasW) loadB(ks + 1, nh);
    if (hasL) loadA(ks + 2, avL);
    const char* bA = smem + (ks & 1) * ABYTES;
#pragma unroll
    for (int s = 0; s < D; ++s) {
      bf16x8 ah[4], al[4];
#pragma unroll
      for (int xf = 0; xf < 4; ++xf) {
        int row = mbase + xf * 16 + rsel;
        ah[xf] = *(const bf16x8*)(bA + (s * 4 + gp) * GPLANE + (row << 4));
        al[xf] = *(const bf16x8*)(bA + HBYTES + (s * 4 + gp) * GPLANE + (row << 4));
      }
#pragma unroll
      for (int nf = 0; nf < NFRAG; ++nf) {
#pragma unroll
        for (int xf = 0; xf < 4; ++xf) {
          acc[nf][xf] = __builtin_amdgcn_mfma_f32_16x16x32_bf16(ch[s][nf], ah[xf], acc[nf][xf], 0, 0, 0);
          acc[nf][xf] = __builtin_amdgcn_mfma_f32_16x16x32_bf16(ch[s][nf], al[xf], acc[nf][xf], 0, 0, 0);
        }
      }
    }
    if (hasW) writeA((ks & 1) ^ 1, avW);
    __syncthreads();
  };

  loadB(0, brA);
  loadA(0, avA);
  writeA(0, avA);
  if (KSUPER > 1) loadA(1, avB);
  __syncthreads();

#pragma unroll 1
  for (int ks = 0; ks < KSUPER; ks += 2) {   // KSUPER even (2 / 32 / 48)
    step(ks,     brA, brB, avB, avA);
    step(ks + 1, brB, brA, avA, avB);
  }

#pragma unroll
  for (int nf = 0; nf < NFRAG; ++nf) {
    int n0 = nbase + nf * 16 + (l >> 4) * 4;
#pragma unroll
    for (int xf = 0; xf < 4; ++xf) {
      int m = mbase + xf * 16 + rsel;
      int xo, yout;
      if constexpr (WIDE) { xo = m; yout = y0; }
      else { xo = m & 63; yout = y0 * NWX + (m >> 6); }
#pragma unroll
      for (int r = 0; r < 4; ++r) {
        float v = acc[nf][xf][r] + bias[n0 + r];
        if constexpr (SPLIT_OUT) {
          if (v < 0.f) v = 0.f;
          outp[((size_t)bb * OC + n0 + r) * OSP + (size_t)(yout + OPAD) * OSR + (xo + OPAD)] =
              packsplit(v);
        } else {
          outf[((size_t)bb * OC + n0 + r) * OSP + (size_t)yout * OSR + xo] = v;
        }
      }
    }
  }
}

// ============ VQ via MFMA (R8, verified; full 3-term split) ========
__global__ __launch_bounds__(256, 2) void vqmm_k(float* __restrict__ zq,
                                                 const float* __restrict__ emb,
                                                 const unsigned* __restrict__ eq,
                                                 const float* __restrict__ enorm,
                                                 unsigned* __restrict__ hist,
                                                 float* __restrict__ ssep) {
  const int tid = threadIdx.x, l = tid & 63, wv = tid >> 6;
  float* zsrc = zq + (size_t)blockIdx.x * 4096;

  __shared__ float zf[64][64];
  __shared__ unsigned zp[4096];
  __shared__ float candd[4][64];
  __shared__ int   candi[4][64];
  __shared__ int   idxf[64];
  __shared__ unsigned hcnt[512];
  __shared__ float wsse[4];

  for (int i = tid; i < 512; i += 256) hcnt[i] = 0;

#pragma unroll
  for (int p = 0; p < 4; ++p) {
    int idx = p * 256 + tid;
    float4 v = *(const float4*)(zsrc + (size_t)idx * 4);
    int n = idx >> 4, d0 = (idx & 15) * 4;
    zf[n][d0 + 0] = v.x; zf[n][d0 + 1] = v.y;
    zf[n][d0 + 2] = v.z; zf[n][d0 + 3] = v.w;
  }
  __syncthreads();
#pragma unroll
  for (int p = 0; p < 16; ++p) {
    int idx = p * 256 + tid;
    int n = idx >> 6, d = idx & 63;
    zp[(n << 6) + ((((d >> 2) ^ (n & 15)) << 2) | (d & 3))] = packsplit(zf[n][d]);
  }
  __syncthreads();

  f32x4 acc[8][4];
#pragma unroll
  for (int nf = 0; nf < 8; ++nf)
#pragma unroll
    for (int xf = 0; xf < 4; ++xf) acc[nf][xf] = (f32x4){0.f, 0.f, 0.f, 0.f};

  const int rsel = l & 15;
#pragma unroll
  for (int ks = 0; ks < 2; ++ks) {
    bf16x8 ah[4], al[4];
    const int gk = ks * 8 + (l >> 4) * 2;
#pragma unroll
    for (int xf = 0; xf < 4; ++xf) {
      int n = xf * 16 + rsel;
      u32x4 p0 = *(const u32x4*)((const char*)zp + (n << 8) + ((gk ^ (n & 15)) << 4));
      u32x4 p1 = *(const u32x4*)((const char*)zp + (n << 8) + (((gk + 1) ^ (n & 15)) << 4));
      ah[xf] = mkfrag(p0, p1, SEL_HI);
      al[xf] = mkfrag(p0, p1, SEL_LO);
    }
#pragma unroll
    for (int nf = 0; nf < 8; ++nf) {
      int fg = wv * 8 + nf;
      u32x4 b0 = *(const u32x4*)(eq + (((size_t)((ks * 32 + fg) * 2 + 0)) << 8) + (l << 2));
      u32x4 b1 = *(const u32x4*)(eq + (((size_t)((ks * 32 + fg) * 2 + 1)) << 8) + (l << 2));
      bf16x8 wh = mkfrag(b0, b1, SEL_HI);
      bf16x8 wl = mkfrag(b0, b1, SEL_LO);
#pragma unroll
      for (int xf = 0; xf < 4; ++xf) {
        acc[nf][xf] = __builtin_amdgcn_mfma_f32_16x16x32_bf16(wh, ah[xf], acc[nf][xf], 0, 0, 0);
        acc[nf][xf] = __builtin_amdgcn_mfma_f32_16x16x32_bf16(wh, al[xf], acc[nf][xf], 0, 0, 0);
        acc[nf][xf] = __builtin_amdgcn_mfma_f32_16x16x32_bf16(wl, ah[xf], acc[nf][xf], 0, 0, 0);
      }
    }
  }

  float en[8][4];
#pragma unroll
  for (int nf = 0; nf < 8; ++nf)
#pragma unroll
    for (int r = 0; r < 4; ++r)
      en[nf][r] = enorm[wv * 128 + nf * 16 + (l >> 4) * 4 + r];

#pragma unroll
  for (int xf = 0; xf < 4; ++xf) {
    float best = 1e30f; int bidx = 0;
#pragma unroll
    for (int nf = 0; nf < 8; ++nf)
#pragma unroll
      for (int r = 0; r < 4; ++r) {
        int k = wv * 128 + nf * 16 + (l >> 4) * 4 + r;
        float dist = en[nf][r] - 2.f * acc[nf][xf][r];
        if (dist < best || (dist == best && k < bidx)) { best = dist; bidx = k; }
      }
#pragma unroll
    for (int off = 16; off <= 32; off <<= 1) {
      float ob = __shfl_xor(best, off, 64);
      int oi = __shfl_xor(bidx, off, 64);
      if (ob < best || (ob == best && oi < bidx)) { best = ob; bidx = oi; }
    }
    if (l < 16) { candd[wv][xf * 16 + l] = best; candi[wv][xf * 16 + l] = bidx; }
  }
  __syncthreads();
  if (tid < 64) {
    float best = candd[0][tid]; int bidx = candi[0][tid];
#pragma unroll
    for (int w = 1; w < 4; ++w) {
      float ob = candd[w][tid]; int oi = candi[w][tid];
      if (ob < best || (ob == best && oi < bidx)) { best = ob; bidx = oi; }
    }
    idxf[tid] = bidx;
    atomicAdd(&hcnt[bidx], 1u);
  }
  __syncthreads();

  float sse = 0.f;
#pragma unroll
  for (int p = 0; p < 16; ++p) {
    int idx = p * 256 + tid;
    int n = idx >> 6, d = idx & 63;
    float q = emb[idxf[n] * 64 + d];
    float z = zf[n][d];
    float df = q - z;
    sse += df * df;
    zsrc[idx] = q;
  }
#pragma unroll
  for (int off = 32; off > 0; off >>= 1) sse += __shfl_down(sse, off, 64);
  if (l == 0) wsse[wv] = sse;

  unsigned* hr = hist + ((blockIdx.x & 7) << 9);
  __syncthreads();
  for (int i = tid; i < 512; i += 256)
    if (hcnt[i]) atomicAdd(&hr[i], hcnt[i]);
  if (tid == 0) ssep[blockIdx.x] = wsse[0] + wsse[1] + wsse[2] + wsse[3];
}

// ================= finalize =================
__global__ void fin_k(const unsigned* __restrict__ hist,
                      const float* __restrict__ ssep,
                      float* __restrict__ out) {
  __shared__ float red[512];
  __shared__ float sred[512];
  int t = threadIdx.x;
  sred[t] = ssep[t] + ssep[t + 512];
  unsigned c = 0;
#pragma unroll
  for (int r = 0; r < 8; ++r) c += hist[(r << 9) + t];
  float p = (float)c * (1.f / 65536.f);
  red[t] = p * logf(p + 1e-10f);
  __syncthreads();
  for (int s = 256; s > 0; s >>= 1) {
    if (t < s) { red[t] += red[t + s]; sred[t] += sred[t + s]; }
    __syncthreads();
  }
  if (t == 0) {
    out[4194304] = 1.25f * sred[0] * (1.f / 4194304.f);
    out[4194305] = expf(-red[0]);
  }
}

extern "C" void kernel_launch(void* const* d_in, const int* in_sizes, int n_in,
                              void* d_out, int out_size, void* d_ws, size_t ws_size,
                              hipStream_t stream) {
  const float* x   = (const float*)d_in[0];
  const float* w1  = (const float*)d_in[1];
  const float* b1  = (const float*)d_in[2];
  const float* w2  = (const float*)d_in[3];
  const float* b2  = (const float*)d_in[4];
  const float* w3  = (const float*)d_in[5];
  const float* b3  = (const float*)d_in[6];
  const float* emb = (const float*)d_in[7];
  // decoder weights unused: reference output ignores x_recon

  float* out = (float*)d_out;
  unsigned* wsu = (unsigned*)d_ws;
  unsigned* h1p = wsu + H1P_OFF;
  unsigned* h2p = wsu + H2P_OFF;
  unsigned short* wq1h = (unsigned short*)(wsu + WQ1H_OFF);
  unsigned short* wq2h = (unsigned short*)(wsu + WQ2H_OFF);
  unsigned short* wq3h = (unsigned short*)(wsu + WQ3H_OFF);
  unsigned* eqp = wsu + EQ_OFF;
  float* enorm = (float*)(wsu + EN_OFF);
  unsigned* hist = wsu + HIST_OFF;
  float* ssep = (float*)(wsu + SSEP_OFF);

  hipMemsetAsync(wsu + HIST_OFF, 0, 4096 * sizeof(unsigned), stream);

  pack_all_k<<<dim3(2976), dim3(256), 0, stream>>>(w1, w2, w3, emb,
                                                   wq1h, wq2h, wq3h, eqp, enorm);
  halo_k<<<dim3(9408), dim3(256), 0, stream>>>(h1p, h2p);

  // conv1: 3->128 via direct-x (XSRC), 4x4 s2 p1, WIDE, D=1
  convmm_k<4, 16, 128, 258, 260, 2, 2, 2, 7, true, 132, 17160, 1, true, 1, true>
      <<<dim3(2048), dim3(256), 0, stream>>>(nullptr, x, wq1h, b1, h1p, nullptr);
  // conv2: 128->256, 4x4 s2 p1 (NWX=1, NWC=4), D=2
  convmm_k<128, 16, 256, 130, 132, 2, 1, 4, 6, false, 68, 4488, 1, true, 2, false>
      <<<dim3(1024), dim3(256), 0, stream>>>(h1p, nullptr, wq2h, b2, h2p, nullptr);
  // conv3: 256->64, 3x3 s1 p1 (NWX=2, NWC=2), D=2
  convmm_k<256, 12, 64, 66, 68, 1, 2, 2, 5, false, 64, 4096, 0, false, 2, false>
      <<<dim3(512), dim3(256), 0, stream>>>(h2p, nullptr, wq3h, b3, nullptr, out);

  vqmm_k<<<dim3(1024), dim3(256), 0, stream>>>(out, emb, eqp, enorm, hist, ssep);
  fin_k<<<dim3(1), dim3(512), 0, stream>>>(hist, ssep, out);
}

// Round 22
// 283.188 us; speedup vs baseline: 1.3222x; 1.0182x over previous
//
#include <hip/hip_runtime.h>
#include <math.h>

typedef __attribute__((ext_vector_type(8))) short bf16x8;
typedef __attribute__((ext_vector_type(4))) float f32x4;
typedef __attribute__((ext_vector_type(4))) unsigned u32x4;
typedef __attribute__((ext_vector_type(2))) unsigned u32x2;

// ---------------- workspace layout (u32 offsets) ----------------
#define H1P_OFF  0ull
#define H2P_OFF  35143680ull
#define WQ2H_OFF 53526528ull
#define WQ3H_OFF 54050816ull
#define EQ_OFF   54247424ull
#define EN_OFF   54280192ull
#define HIST_OFF 54280704ull   // 8 replicas x 512
#define SSEP_OFF 54284800ull   // 1024 partials
#define WQ1H_OFF 54285824ull

__device__ inline unsigned short f2bf(float f) {
  unsigned u = __builtin_bit_cast(unsigned, f);
  return (unsigned short)((u + 0x7fffu + ((u >> 16) & 1u)) >> 16);  // RNE
}
__device__ inline float bf2f(unsigned short h) {
  return __builtin_bit_cast(float, (unsigned)h << 16);
}
__device__ inline unsigned packsplit(float v) {
  unsigned short h = f2bf(v);
  unsigned short l = f2bf(v - bf2f(h));
  return (unsigned)h | ((unsigned)l << 16);
}
#define SEL_HI 0x05040100u
#define SEL_LO 0x07060302u
__device__ inline bf16x8 mkfrag(const u32x4 p, const u32x4 q, unsigned sel) {
  u32x4 r;
  r[0] = __builtin_amdgcn_perm(p[1], p[0], sel);
  r[1] = __builtin_amdgcn_perm(p[3], p[2], sel);
  r[2] = __builtin_amdgcn_perm(q[1], q[0], sel);
  r[3] = __builtin_amdgcn_perm(q[3], q[2], sel);
  return __builtin_bit_cast(bf16x8, r);
}

// ======= merged weight/emb repack (one launch) ===============================
__global__ void pack_all_k(const float* __restrict__ w1, const float* __restrict__ w2,
                           const float* __restrict__ w3, const float* __restrict__ emb,
                           unsigned short* __restrict__ wh1, unsigned short* __restrict__ wh2,
                           unsigned short* __restrict__ wh3, unsigned* __restrict__ eq,
                           float* __restrict__ enorm) {
  int blk = blockIdx.x;
  if (blk < 2048) {                      // wq2: 524288 u16
    int i = blk * 256 + threadIdx.x;
    int j = i & 7, l = (i >> 3) & 63, fg = (i >> 9) & 15, ks = i >> 13;
    int row = fg * 16 + (l & 15);
    int k = ks * 32 + (l >> 4) * 8 + j;
    wh2[i] = f2bf(w2[row * 2048 + k]);
  } else if (blk < 2816) {               // wq3: 196608 u16
    int i = (blk - 2048) * 256 + threadIdx.x;
    int j = i & 7, l = (i >> 3) & 63, fg = (i >> 9) & 3, ks = i >> 11;
    int row = fg * 16 + (l & 15);
    int k = ks * 32 + (l >> 4) * 8 + j;
    int ci = k / 12, rb = k - ci * 12, kh = rb >> 2, kw = rb & 3;
    wh3[i] = (kw < 3) ? f2bf(w3[((row * 256 + ci) * 3 + kh) * 3 + kw]) : (unsigned short)0;
  } else if (blk < 2848) {               // wq1: 8192 u16
    int i = (blk - 2816) * 256 + threadIdx.x;
    int j = i & 7, l = (i >> 3) & 63, fg = (i >> 9) & 7, ks = i >> 12;
    int row = fg * 16 + (l & 15);
    int k = ks * 32 + (l >> 4) * 8 + j;
    int ci = k >> 4, r = k & 15, kh = r >> 2, kw = r & 3;
    wh1[i] = (ci < 3) ? f2bf(w1[((row * 3 + ci) * 4 + kh) * 4 + kw]) : (unsigned short)0;
  } else {                               // eq: 32768 u32 + enorm 512
    int i = (blk - 2848) * 256 + threadIdx.x;
    if (i < 32768) {
      int e = i & 3, l = (i >> 2) & 63, j = (i >> 8) & 1, fg = (i >> 9) & 31, ks = i >> 14;
      int row = fg * 16 + (l & 15);
      int d = ks * 32 + (l >> 4) * 8 + j * 4 + e;
      eq[i] = packsplit(emb[row * 64 + d]);
    }
    if (i < 512) {
      float s = 0.f;
#pragma unroll
      for (int d = 0; d < 64; ++d) { float e = emb[i * 64 + d]; s += e * e; }
      enorm[i] = s;
    }
  }
}

// ================= halo zeroing =================
__global__ void halo_k(unsigned* __restrict__ h1p, unsigned* __restrict__ h2p) {
  int i = blockIdx.x * 256 + threadIdx.x;
  if (i < 2048 * 520) {
    int p = i / 520, c = i - p * 520; int r, cc;
    if (c < 132)      { r = 0;   cc = c; }
    else if (c < 264) { r = 129; cc = c - 132; }
    else if (c < 392) { r = c - 264 + 1; cc = 0; }
    else              { r = c - 392 + 1; cc = 129; }
    h1p[(size_t)p * 130 * 132 + r * 132 + cc] = 0u;
  } else {
    int j = i - 2048 * 520;
    if (j >= 4096 * 328) return;
    int p = j / 328, c = j - p * 328; int r, cc;
    if (c < 68)       { r = 0;  cc = c; }
    else if (c < 136) { r = 65; cc = c - 68; }
    else { int c2 = c - 136; int which = c2 >> 6; r = 1 + (c2 & 63);
           cc = (which == 0) ? 0 : (which == 1 ? 65 : 66); }
    h2p[(size_t)p * 66 * 68 + r * 68 + cc] = 0u;
  }
}

// ====== pipelined implicit-GEMM conv, 2-term split-bf16 MFMA ==================
// R22: hoisted A-frag reads — ALL D*8 ds_reads issued at superstep top, then
// all MFMAs (s=0 MFMAs overlap s=1 read latency via counted lgkmcnt). Pure
// register change (+32 VGPR, ~204 unified <= 256). All else = R19/R21.
template <int IC, int KHW, int OC, int IHP, int IWP, int S, int NWX, int NWC,
          int YB, bool WIDE, int OSR, int OSP, int OPAD, bool SPLIT_OUT, int D, bool XSRC>
__global__ __launch_bounds__(256, 2) void convmm_k(const unsigned* __restrict__ inp,
                                                   const float* __restrict__ xsrc,
                                                   const unsigned short* __restrict__ wqh,
                                                   const float* __restrict__ bias,
                                                   unsigned* __restrict__ outp,
                                                   float* __restrict__ outf) {
  constexpr int K = IC * KHW;
  constexpr int KSUPER = K / (32 * D);
  constexpr int FGTOT = OC / 16;
  constexpr int NFRAG = OC / NWC / 16;
  constexpr int MR = 64 * NWX;
  constexpr int CELLS = (MR / 32) * D;
  constexpr int GPLANE = MR * 16;
  constexpr int HBYTES = MR * 64 * D;
  constexpr int ABYTES = MR * 128 * D;
  constexpr int LOG2NWX = (NWX == 2) ? 1 : 0;
  constexpr int LOG2MR = (NWX == 2) ? 7 : 6;

  __shared__ char smem[2 * ABYTES];

  const int tid = threadIdx.x, l = tid & 63, wv = tid >> 6;
  const int orig = (blockIdx.x & 7) * ((int)gridDim.x >> 3) + (blockIdx.x >> 3);
  const int bb = orig >> YB;
  const int y0 = orig & ((1 << YB) - 1);
  const int rsel = l & 15, gp = l >> 4;
  const int mbase = (wv & (NWX - 1)) * 64;
  const int fgbase = (wv >> LOG2NWX) * NFRAG;
  const int nbase = fgbase * 16;

  const int arow = tid & (MR - 1);
  int qs[CELLS];
  const unsigned* abase[CELLS];
#pragma unroll
  for (int c = 0; c < CELLS; ++c) {
    qs[c] = (tid >> LOG2MR) * CELLS + c;
    if constexpr (KHW == 16 && !XSRC) {
      int ci0 = qs[c] >> 2, kh = qs[c] & 3;
      abase[c] = inp + (((size_t)bb * IC + ci0) * IHP + (S * y0 + kh)) * IWP + S * arow;
    }
  }

  f32x4 acc[NFRAG][4];
#pragma unroll
  for (int nf = 0; nf < NFRAG; ++nf)
#pragma unroll
    for (int xf = 0; xf < 4; ++xf) acc[nf][xf] = (f32x4){0.f, 0.f, 0.f, 0.f};

  unsigned avA[CELLS][4], avB[CELLS][4];
  bf16x8 brA[D][NFRAG], brB[D][NFRAG];

  auto loadA = [&](int ks, unsigned (&av)[CELLS][4]) {
#pragma unroll
    for (int c = 0; c < CELLS; ++c) {
      if constexpr (XSRC) {
        int ci = (qs[c] >> 2) + 2 * D * ks;
        int kh = qs[c] & 3;
        int iy = S * y0 + kh - 1;
        bool yok = (ci < 3) && ((unsigned)iy < 256u);
        const float* xp = xsrc + ((size_t)(bb * 3 + ci) * 256 + iy) * 256;
#pragma unroll
        for (int e = 0; e < 4; ++e) {
          int ix = S * arow + e - 1;
          av[c][e] = (yok && (unsigned)ix < 256u) ? packsplit(xp[ix]) : 0u;
        }
      } else if constexpr (KHW == 16) {
        const unsigned* p = abase[c];
        av[c][0] = p[0]; av[c][1] = p[1]; av[c][2] = p[2]; av[c][3] = p[3];
        abase[c] += (size_t)(2 * D) * IHP * IWP;
      } else {                                   // KHW == 12 (conv3)
        int k = ks * (32 * D) + qs[c] * 4;
        int ci = (k * 5462) >> 16;
        int rb = k - ci * 12;
        int kh = rb >> 2;
        int yl = arow >> 6, x = arow & 63;
        const unsigned* p = inp + (((size_t)bb * IC + ci) * IHP + (y0 * 2 + yl + kh)) * IWP + x;
        av[c][0] = p[0]; av[c][1] = p[1]; av[c][2] = p[2]; av[c][3] = p[3];
      }
    }
  };
  auto writeA = [&](int buf, unsigned (&av)[CELLS][4]) {
    char* base = smem + buf * ABYTES;
#pragma unroll
    for (int cp = 0; cp < CELLS / 2; ++cp) {
      int q0 = qs[2 * cp];
      int off = (q0 >> 1) * GPLANE + (arow << 4);
      u32x4 h, lo;
      h[0]  = __builtin_amdgcn_perm(av[2 * cp][1],     av[2 * cp][0],     SEL_HI);
      h[1]  = __builtin_amdgcn_perm(av[2 * cp][3],     av[2 * cp][2],     SEL_HI);
      h[2]  = __builtin_amdgcn_perm(av[2 * cp + 1][1], av[2 * cp + 1][0], SEL_HI);
      h[3]  = __builtin_amdgcn_perm(av[2 * cp + 1][3], av[2 * cp + 1][2], SEL_HI);
      lo[0] = __builtin_amdgcn_perm(av[2 * cp][1],     av[2 * cp][0],     SEL_LO);
      lo[1] = __builtin_amdgcn_perm(av[2 * cp][3],     av[2 * cp][2],     SEL_LO);
      lo[2] = __builtin_amdgcn_perm(av[2 * cp + 1][1], av[2 * cp + 1][0], SEL_LO);
      lo[3] = __builtin_amdgcn_perm(av[2 * cp + 1][3], av[2 * cp + 1][2], SEL_LO);
      *(u32x4*)(base + off) = h;
      *(u32x4*)(base + HBYTES + off) = lo;
    }
  };
  auto loadB = [&](int ks, bf16x8 (&bh)[D][NFRAG]) {
#pragma unroll
    for (int s = 0; s < D; ++s)
#pragma unroll
      for (int nf = 0; nf < NFRAG; ++nf) {
        size_t idx = (((size_t)((ks * D + s) * FGTOT + fgbase + nf) * 64) + l) * 8;
        bh[s][nf] = *(const bf16x8*)(wqh + idx);
      }
  };
  auto step = [&](int ks, bf16x8 (&ch)[D][NFRAG], bf16x8 (&nh)[D][NFRAG],
                  unsigned (&avW)[CELLS][4], unsigned (&avL)[CELLS][4]) {
    const bool hasW = (ks + 1 < KSUPER);
    const bool hasL = (ks + 2 < KSUPER);
    if (hasW) loadB(ks + 1, nh);
    if (hasL) loadA(ks + 2, avL);
    const char* bA = smem + (ks & 1) * ABYTES;
    // hoist ALL frag reads: s=0 MFMAs can start while s>=1 reads in flight
    bf16x8 ah[D][4], al[D][4];
#pragma unroll
    for (int s = 0; s < D; ++s)
#pragma unroll
      for (int xf = 0; xf < 4; ++xf) {
        int row = mbase + xf * 16 + rsel;
        ah[s][xf] = *(const bf16x8*)(bA + (s * 4 + gp) * GPLANE + (row << 4));
        al[s][xf] = *(const bf16x8*)(bA + HBYTES + (s * 4 + gp) * GPLANE + (row << 4));
      }
#pragma unroll
    for (int s = 0; s < D; ++s) {
#pragma unroll
      for (int nf = 0; nf < NFRAG; ++nf) {
#pragma unroll
        for (int xf = 0; xf < 4; ++xf) {
          acc[nf][xf] = __builtin_amdgcn_mfma_f32_16x16x32_bf16(ch[s][nf], ah[s][xf], acc[nf][xf], 0, 0, 0);
          acc[nf][xf] = __builtin_amdgcn_mfma_f32_16x16x32_bf16(ch[s][nf], al[s][xf], acc[nf][xf], 0, 0, 0);
        }
      }
    }
    if (hasW) writeA((ks & 1) ^ 1, avW);
    __syncthreads();
  };

  loadB(0, brA);
  loadA(0, avA);
  writeA(0, avA);
  if (KSUPER > 1) loadA(1, avB);
  __syncthreads();

#pragma unroll 1
  for (int ks = 0; ks < KSUPER; ks += 2) {   // KSUPER even (2 / 32 / 48)
    step(ks,     brA, brB, avB, avA);
    step(ks + 1, brB, brA, avA, avB);
  }

#pragma unroll
  for (int nf = 0; nf < NFRAG; ++nf) {
    int n0 = nbase + nf * 16 + (l >> 4) * 4;
#pragma unroll
    for (int xf = 0; xf < 4; ++xf) {
      int m = mbase + xf * 16 + rsel;
      int xo, yout;
      if constexpr (WIDE) { xo = m; yout = y0; }
      else { xo = m & 63; yout = y0 * NWX + (m >> 6); }
#pragma unroll
      for (int r = 0; r < 4; ++r) {
        float v = acc[nf][xf][r] + bias[n0 + r];
        if constexpr (SPLIT_OUT) {
          if (v < 0.f) v = 0.f;
          outp[((size_t)bb * OC + n0 + r) * OSP + (size_t)(yout + OPAD) * OSR + (xo + OPAD)] =
              packsplit(v);
        } else {
          outf[((size_t)bb * OC + n0 + r) * OSP + (size_t)yout * OSR + xo] = v;
        }
      }
    }
  }
}

// ============ VQ via MFMA (R8, verified; full 3-term split) ========
__global__ __launch_bounds__(256, 2) void vqmm_k(float* __restrict__ zq,
                                                 const float* __restrict__ emb,
                                                 const unsigned* __restrict__ eq,
                                                 const float* __restrict__ enorm,
                                                 unsigned* __restrict__ hist,
                                                 float* __restrict__ ssep) {
  const int tid = threadIdx.x, l = tid & 63, wv = tid >> 6;
  float* zsrc = zq + (size_t)blockIdx.x * 4096;

  __shared__ float zf[64][64];
  __shared__ unsigned zp[4096];
  __shared__ float candd[4][64];
  __shared__ int   candi[4][64];
  __shared__ int   idxf[64];
  __shared__ unsigned hcnt[512];
  __shared__ float wsse[4];

  for (int i = tid; i < 512; i += 256) hcnt[i] = 0;

#pragma unroll
  for (int p = 0; p < 4; ++p) {
    int idx = p * 256 + tid;
    float4 v = *(const float4*)(zsrc + (size_t)idx * 4);
    int n = idx >> 4, d0 = (idx & 15) * 4;
    zf[n][d0 + 0] = v.x; zf[n][d0 + 1] = v.y;
    zf[n][d0 + 2] = v.z; zf[n][d0 + 3] = v.w;
  }
  __syncthreads();
#pragma unroll
  for (int p = 0; p < 16; ++p) {
    int idx = p * 256 + tid;
    int n = idx >> 6, d = idx & 63;
    zp[(n << 6) + ((((d >> 2) ^ (n & 15)) << 2) | (d & 3))] = packsplit(zf[n][d]);
  }
  __syncthreads();

  f32x4 acc[8][4];
#pragma unroll
  for (int nf = 0; nf < 8; ++nf)
#pragma unroll
    for (int xf = 0; xf < 4; ++xf) acc[nf][xf] = (f32x4){0.f, 0.f, 0.f, 0.f};

  const int rsel = l & 15;
#pragma unroll
  for (int ks = 0; ks < 2; ++ks) {
    bf16x8 ah[4], al[4];
    const int gk = ks * 8 + (l >> 4) * 2;
#pragma unroll
    for (int xf = 0; xf < 4; ++xf) {
      int n = xf * 16 + rsel;
      u32x4 p0 = *(const u32x4*)((const char*)zp + (n << 8) + ((gk ^ (n & 15)) << 4));
      u32x4 p1 = *(const u32x4*)((const char*)zp + (n << 8) + (((gk + 1) ^ (n & 15)) << 4));
      ah[xf] = mkfrag(p0, p1, SEL_HI);
      al[xf] = mkfrag(p0, p1, SEL_LO);
    }
#pragma unroll
    for (int nf = 0; nf < 8; ++nf) {
      int fg = wv * 8 + nf;
      u32x4 b0 = *(const u32x4*)(eq + (((size_t)((ks * 32 + fg) * 2 + 0)) << 8) + (l << 2));
      u32x4 b1 = *(const u32x4*)(eq + (((size_t)((ks * 32 + fg) * 2 + 1)) << 8) + (l << 2));
      bf16x8 wh = mkfrag(b0, b1, SEL_HI);
      bf16x8 wl = mkfrag(b0, b1, SEL_LO);
#pragma unroll
      for (int xf = 0; xf < 4; ++xf) {
        acc[nf][xf] = __builtin_amdgcn_mfma_f32_16x16x32_bf16(wh, ah[xf], acc[nf][xf], 0, 0, 0);
        acc[nf][xf] = __builtin_amdgcn_mfma_f32_16x16x32_bf16(wh, al[xf], acc[nf][xf], 0, 0, 0);
        acc[nf][xf] = __builtin_amdgcn_mfma_f32_16x16x32_bf16(wl, ah[xf], acc[nf][xf], 0, 0, 0);
      }
    }
  }

  float en[8][4];
#pragma unroll
  for (int nf = 0; nf < 8; ++nf)
#pragma unroll
    for (int r = 0; r < 4; ++r)
      en[nf][r] = enorm[wv * 128 + nf * 16 + (l >> 4) * 4 + r];

#pragma unroll
  for (int xf = 0; xf < 4; ++xf) {
    float best = 1e30f; int bidx = 0;
#pragma unroll
    for (int nf = 0; nf < 8; ++nf)
#pragma unroll
      for (int r = 0; r < 4; ++r) {
        int k = wv * 128 + nf * 16 + (l >> 4) * 4 + r;
        float dist = en[nf][r] - 2.f * acc[nf][xf][r];
        if (dist < best || (dist == best && k < bidx)) { best = dist; bidx = k; }
      }
#pragma unroll
    for (int off = 16; off <= 32; off <<= 1) {
      float ob = __shfl_xor(best, off, 64);
      int oi = __shfl_xor(bidx, off, 64);
      if (ob < best || (ob == best && oi < bidx)) { best = ob; bidx = oi; }
    }
    if (l < 16) { candd[wv][xf * 16 + l] = best; candi[wv][xf * 16 + l] = bidx; }
  }
  __syncthreads();
  if (tid < 64) {
    float best = candd[0][tid]; int bidx = candi[0][tid];
#pragma unroll
    for (int w = 1; w < 4; ++w) {
      float ob = candd[w][tid]; int oi = candi[w][tid];
      if (ob < best || (ob == best && oi < bidx)) { best = ob; bidx = oi; }
    }
    idxf[tid] = bidx;
    atomicAdd(&hcnt[bidx], 1u);
  }
  __syncthreads();

  float sse = 0.f;
#pragma unroll
  for (int p = 0; p < 16; ++p) {
    int idx = p * 256 + tid;
    int n = idx >> 6, d = idx & 63;
    float q = emb[idxf[n] * 64 + d];
    float z = zf[n][d];
    float df = q - z;
    sse += df * df;
    zsrc[idx] = q;
  }
#pragma unroll
  for (int off = 32; off > 0; off >>= 1) sse += __shfl_down(sse, off, 64);
  if (l == 0) wsse[wv] = sse;

  unsigned* hr = hist + ((blockIdx.x & 7) << 9);
  __syncthreads();
  for (int i = tid; i < 512; i += 256)
    if (hcnt[i]) atomicAdd(&hr[i], hcnt[i]);
  if (tid == 0) ssep[blockIdx.x] = wsse[0] + wsse[1] + wsse[2] + wsse[3];
}

// ================= finalize =================
__global__ void fin_k(const unsigned* __restrict__ hist,
                      const float* __restrict__ ssep,
                      float* __restrict__ out) {
  __shared__ float red[512];
  __shared__ float sred[512];
  int t = threadIdx.x;
  sred[t] = ssep[t] + ssep[t + 512];
  unsigned c = 0;
#pragma unroll
  for (int r = 0; r < 8; ++r) c += hist[(r << 9) + t];
  float p = (float)c * (1.f / 65536.f);
  red[t] = p * logf(p + 1e-10f);
  __syncthreads();
  for (int s = 256; s > 0; s >>= 1) {
    if (t < s) { red[t] += red[t + s]; sred[t] += sred[t + s]; }
    __syncthreads();
  }
  if (t == 0) {
    out[4194304] = 1.25f * sred[0] * (1.f / 4194304.f);
    out[4194305] = expf(-red[0]);
  }
}

extern "C" void kernel_launch(void* const* d_in, const int* in_sizes, int n_in,
                              void* d_out, int out_size, void* d_ws, size_t ws_size,
                              hipStream_t stream) {
  const float* x   = (const float*)d_in[0];
  const float* w1  = (const float*)d_in[1];
  const float* b1  = (const float*)d_in[2];
  const float* w2  = (const float*)d_in[3];
  const float* b2  = (const float*)d_in[4];
  const float* w3  = (const float*)d_in[5];
  const float* b3  = (const float*)d_in[6];
  const float* emb = (const float*)d_in[7];
  // decoder weights unused: reference output ignores x_recon

  float* out = (float*)d_out;
  unsigned* wsu = (unsigned*)d_ws;
  unsigned* h1p = wsu + H1P_OFF;
  unsigned* h2p = wsu + H2P_OFF;
  unsigned short* wq1h = (unsigned short*)(wsu + WQ1H_OFF);
  unsigned short* wq2h = (unsigned short*)(wsu + WQ2H_OFF);
  unsigned short* wq3h = (unsigned short*)(wsu + WQ3H_OFF);
  unsigned* eqp = wsu + EQ_OFF;
  float* enorm = (float*)(wsu + EN_OFF);
  unsigned* hist = wsu + HIST_OFF;
  float* ssep = (float*)(wsu + SSEP_OFF);

  hipMemsetAsync(wsu + HIST_OFF, 0, 4096 * sizeof(unsigned), stream);

  pack_all_k<<<dim3(2976), dim3(256), 0, stream>>>(w1, w2, w3, emb,
                                                   wq1h, wq2h, wq3h, eqp, enorm);
  halo_k<<<dim3(9408), dim3(256), 0, stream>>>(h1p, h2p);

  // conv1: 3->128 via direct-x (XSRC), 4x4 s2 p1, WIDE, D=1
  convmm_k<4, 16, 128, 258, 260, 2, 2, 2, 7, true, 132, 17160, 1, true, 1, true>
      <<<dim3(2048), dim3(256), 0, stream>>>(nullptr, x, wq1h, b1, h1p, nullptr);
  // conv2: 128->256, 4x4 s2 p1 (NWX=1, NWC=4), D=2
  convmm_k<128, 16, 256, 130, 132, 2, 1, 4, 6, false, 68, 4488, 1, true, 2, false>
      <<<dim3(1024), dim3(256), 0, stream>>>(h1p, nullptr, wq2h, b2, h2p, nullptr);
  // conv3: 256->64, 3x3 s1 p1 (NWX=2, NWC=2), D=2
  convmm_k<256, 12, 64, 66, 68, 1, 2, 2, 5, false, 64, 4096, 0, false, 2, false>
      <<<dim3(512), dim3(256), 0, stream>>>(h2p, nullptr, wq3h, b3, nullptr, out);

  vqmm_k<<<dim3(1024), dim3(256), 0, stream>>>(out, emb, eqp, enorm, hist, ssep);
  fin_k<<<dim3(1), dim3(512), 0, stream>>>(hist, ssep, out);
}